// Round 6
// baseline (278.570 us; speedup 1.0000x reference)
//
#include <hip/hip_runtime.h>
#include <math.h>

#define LSLOPE 0.01f

__device__ __forceinline__ float lrelu(float x){ return x >= 0.f ? x : LSLOPE * x; }

typedef __attribute__((ext_vector_type(8))) short short8;
typedef __attribute__((ext_vector_type(4))) float f32x4;

__device__ __forceinline__ unsigned short f2bf(float f){
  union { float f; unsigned u; } v; v.f = f;
  unsigned r = v.u + 0x7FFFu + ((v.u >> 16) & 1u);
  return (unsigned short)(r >> 16);
}

constexpr int B    = 16;
constexpr int CIN  = 256;
constexpr int COUT = 256;
constexpr int HH   = 64;
constexpr int WW   = 64;
constexpr int FD   = 128;
constexpr int LAT  = 128;
constexpr int WPS  = CIN * 9;           // 2304
constexpr int WTOT = COUT * WPS;        // 589824
constexpr int NPART = 64;

// ---- workspace layout (in floats) ----
constexpr int OFF_STAT  = 0;
constexpr int OFF_BMEAN = 16;
constexpr int OFF_BSTD  = 32;
constexpr int OFF_OPS   = 64;
constexpr int OFF_OPQ   = 128;
constexpr int OFF_PS    = 192;
constexpr int OFF_PQ    = 1216;
constexpr int OFF_H     = 2240;
constexpr int OFF_STYLE = 4288;
constexpr int OFF_NBIAS = 78016;
constexpr int OFF_NW    = 82176;                               // bf16 [16][9][256][256]
constexpr int OFF_YTR   = OFF_NW + (B * 9 * COUT * CIN) / 2;   // bf16 [16][64][64][256]

// ---------- global weight stats ----------
__global__ void k_ori_part(const float* __restrict__ ow, float* psum, float* psq){
  const int p = blockIdx.x;
  const int chunk = WTOT / NPART;
  const int base = p * chunk;
  float s = 0.f, q = 0.f;
  for (int i = threadIdx.x; i < chunk; i += 256){
    float v = ow[base + i];
    s += v; q += v * v;
  }
  __shared__ float ss[256], sq[256];
  ss[threadIdx.x] = s; sq[threadIdx.x] = q; __syncthreads();
  for (int st = 128; st > 0; st >>= 1){
    if (threadIdx.x < st){ ss[threadIdx.x] += ss[threadIdx.x + st]; sq[threadIdx.x] += sq[threadIdx.x + st]; }
    __syncthreads();
  }
  if (threadIdx.x == 0){ psum[p] = ss[0]; psq[p] = sq[0]; }
}

__global__ void k_ori_final(const float* __restrict__ psum, const float* __restrict__ psq, float* stat){
  int t = threadIdx.x;
  float s = psum[t], q = psq[t];
  for (int o = 32; o > 0; o >>= 1){ s += __shfl_down(s, o); q += __shfl_down(q, o); }
  if (t == 0){
    const float N = (float)WTOT;
    stat[0] = s / N;
    stat[1] = sqrtf((q - s * s / N) / (N - 1.f));
  }
}

// ---------- style MLP ----------
__global__ void k_style_h(const float* __restrict__ finger, const float* __restrict__ sw1, float* __restrict__ h){
  int idx = blockIdx.x * blockDim.x + threadIdx.x;
  if (idx >= B * LAT) return;
  int b = idx / LAT, l = idx - b * LAT;
  float acc = 0.f;
  for (int f = 0; f < FD; ++f) acc += finger[b * FD + f] * sw1[l * FD + f];
  h[idx] = lrelu(acc);
}

__global__ void k_style(const float* __restrict__ h, const float* __restrict__ sw2, float* __restrict__ style){
  int idx = blockIdx.x * blockDim.x + threadIdx.x;
  if (idx >= B * 2 * WPS) return;
  int b = idx / (2 * WPS), j = idx - b * 2 * WPS;
  float acc = 0.f;
  for (int l = 0; l < LAT; ++l) acc += h[b * LAT + l] * sw2[j * LAT + l];
  style[idx] = acc;
}

// ---------- per-sample bias ----------
__global__ void k_bias(const float* __restrict__ finger, const float* __restrict__ bw1,
                       const float* __restrict__ bw2, const float* __restrict__ fbias,
                       const float* __restrict__ bmask, const float* __restrict__ obias,
                       float* __restrict__ nbias){
  __shared__ float hb[COUT];
  const int b = blockIdx.x, o = threadIdx.x;
  float acc = 0.f;
  for (int f = 0; f < FD; ++f) acc += finger[b * FD + f] * bw1[o * FD + f];
  hb[o] = lrelu(acc);
  __syncthreads();
  float t = 0.f;
  for (int c = 0; c < COUT; ++c) t += hb[c] * bw2[o * COUT + c];
  t = lrelu(t);
  float sb = fbias[o] * t;
  float fwb = (6.f - fminf(fmaxf(bmask[o], 0.f), 6.f)) * (1.f / 6.f);
  nbias[b * COUT + o] = (1.f - fwb) * obias[o] + fwb * sb;
}

// ---------- per-sample w1 stats ----------
__global__ void k_w1_part(const float* __restrict__ ow, const float* __restrict__ fwgt,
                          const float* __restrict__ wmask, const float* __restrict__ style,
                          float* psum, float* psq){
  const int p = blockIdx.x, b = blockIdx.y;
  const float* st = style + b * 2 * WPS;
  const int chunk = WTOT / NPART;
  const int base = p * chunk;
  float s = 0.f, q = 0.f;
  for (int ii = threadIdx.x; ii < chunk; ii += 256){
    int idx = base + ii;
    int o = idx / WPS; int rem = idx - o * WPS; int ci = rem / 9;
    float fw = (6.f - fminf(fmaxf(wmask[o * CIN + ci], 0.f), 6.f)) * (1.f / 6.f);
    float owv = ow[idx];
    float sw = fwgt[idx] * (st[rem] + 1.f) + st[WPS + rem];
    float w1 = owv + fw * (sw - owv);
    s += w1; q += w1 * w1;
  }
  __shared__ float ss[256], sq[256];
  ss[threadIdx.x] = s; sq[threadIdx.x] = q; __syncthreads();
  for (int st2 = 128; st2 > 0; st2 >>= 1){
    if (threadIdx.x < st2){ ss[threadIdx.x] += ss[threadIdx.x + st2]; sq[threadIdx.x] += sq[threadIdx.x + st2]; }
    __syncthreads();
  }
  if (threadIdx.x == 0){ psum[b * NPART + p] = ss[0]; psq[b * NPART + p] = sq[0]; }
}

__global__ void k_w1_final(const float* __restrict__ psum, const float* __restrict__ psq,
                           float* bmean, float* bstd){
  const int b = blockIdx.x;
  int t = threadIdx.x;
  float s = psum[b * NPART + t], q = psq[b * NPART + t];
  for (int o = 32; o > 0; o >>= 1){ s += __shfl_down(s, o); q += __shfl_down(q, o); }
  if (t == 0){
    const float N = (float)WTOT;
    bmean[b] = s / N;
    bstd[b] = sqrtf((q - s * s / N) / (N - 1.f));
  }
}

// ---------- materialize new_weight bf16, tap-major [b][t][oc][ic], coalesced ----------
__global__ __launch_bounds__(256) void k_new_weight2(const float* __restrict__ ow, const float* __restrict__ fwgt,
                                                     const float* __restrict__ wmask, const float* __restrict__ style,
                                                     const float* __restrict__ stat, const float* __restrict__ bmean,
                                                     const float* __restrict__ bstd, unsigned short* __restrict__ nw){
  __shared__ float ows[WPS];
  __shared__ float fws[WPS];
  const int oc = blockIdx.x, b = blockIdx.y;
  const int tid = threadIdx.x;               // = ic
  const float mean_ori = stat[0], std_ori = stat[1];
  const float bm = bmean[b], bs = bstd[b];
  const float* owr = ow + (size_t)oc * WPS;
  const float* fwr = fwgt + (size_t)oc * WPS;
  for (int i = tid; i < WPS; i += 256){ ows[i] = owr[i]; fws[i] = fwr[i]; }
  const float fw = (6.f - fminf(fmaxf(wmask[oc * CIN + tid], 0.f), 6.f)) * (1.f / 6.f);
  const float* st = style + b * 2 * WPS;
  __syncthreads();
  #pragma unroll
  for (int t = 0; t < 9; ++t){
    int rem = tid * 9 + t;
    float owv = ows[rem];
    float sw = fws[rem] * (st[rem] + 1.f) + st[WPS + rem];
    float w1 = owv + fw * (sw - owv);
    float w2 = (w1 - bm) / bs * std_ori + mean_ori;
    nw[((size_t)(b * 9 + t) * COUT + oc) * CIN + tid] = f2bf(owv + fw * (w2 - owv));
  }
}

// ---------- y -> channel-last bf16: ytr[b][h][w][ic] ----------
constexpr int PADT = 264;
__global__ __launch_bounds__(256) void k_ytr(const float* __restrict__ y, unsigned short* __restrict__ ytr){
  __shared__ unsigned short t[64 * PADT];
  const int h = blockIdx.x, b = blockIdx.y;
  const int tid = threadIdx.x;
  const float* src = y + (size_t)b * CIN * HH * WW + h * WW;
  #pragma unroll
  for (int k = 0; k < 16; ++k){
    int idx = tid + k * 256;
    int ic = idx >> 4, w4 = (idx & 15) * 4;
    float4 v = *(const float4*)(src + (size_t)ic * HH * WW + w4);
    t[(w4 + 0) * PADT + ic] = f2bf(v.x);
    t[(w4 + 1) * PADT + ic] = f2bf(v.y);
    t[(w4 + 2) * PADT + ic] = f2bf(v.z);
    t[(w4 + 3) * PADT + ic] = f2bf(v.w);
  }
  __syncthreads();
  unsigned short* dst = ytr + (((size_t)b * HH + h) * WW) * CIN;
  #pragma unroll
  for (int k = 0; k < 8; ++k){
    int idx = tid + k * 256;
    int w = idx >> 5, icg = (idx & 31) * 8;
    uint4 v = *(const uint4*)(&t[w * PADT + icg]);
    *(uint4*)(dst + (size_t)w * CIN + icg) = v;
  }
}

// ---------- MFMA implicit-GEMM conv, 128x128 tile + T14 async-stage prefetch ----------
// grid (32 hw-tiles, 2 oc-tiles, 16 b); 256 thr = 4 waves (2x2).
// 24 linearized iterations (dh 3 x icb 8). Each iter: issue next iter's 9 global
// uint4 loads into regs; compute 3 taps x 16 MFMA from LDS; barrier; write regs->LDS;
// barrier. Load latency hides under the MFMA phase.
__global__ __launch_bounds__(256) void k_conv_mfma5(const unsigned short* __restrict__ ytr,
                                                    const unsigned short* __restrict__ nw,
                                                    const float* __restrict__ nbias,
                                                    float* __restrict__ out){
  constexpr int APAD = 44;   // 88B stride -> 22-bank starts, distinct mod 32
  constexpr int BPAD = 36;   // 72B stride -> 18-bank starts, distinct mod 32
  __shared__ unsigned short Wa[3 * 128 * APAD];   // 33792 B
  __shared__ unsigned short Yt[2 * 68 * BPAD];    //  9792 B
  __shared__ float bsh[128];

  const int hwt = blockIdx.x;
  const int oc0 = blockIdx.y * 128;
  const int b   = blockIdx.z;
  const int tid = threadIdx.x;
  const int lane = tid & 63, wid = tid >> 6;
  const int wr = wid >> 1, wc = wid & 1;
  const int hw0 = hwt * 128;
  const int h0  = hwt * 2;

  if (tid < 128) bsh[tid] = nbias[b * COUT + oc0 + tid];

  f32x4 acc[4][4];
  #pragma unroll
  for (int i = 0; i < 4; ++i)
    #pragma unroll
    for (int j = 0; j < 4; ++j) acc[i][j] = (f32x4){0.f, 0.f, 0.f, 0.f};

  const unsigned short* ytb = ytr + (size_t)b * HH * WW * CIN;
  const unsigned short* nwb = nw + ((size_t)(b * 9) * COUT + oc0) * CIN;

  // ---- tid-invariant staging geometry (hoisted out of the loop) ----
  // A chunks: idx = tid + j*256, j<6; tap=idx>>9, row=(idx&511)>>2, ch=idx&3
  int a_goff[6], a_lds[6];
  #pragma unroll
  for (int j = 0; j < 6; ++j){
    int idx = tid + j * 256;
    int tap = idx >> 9, r2 = idx & 511, row = r2 >> 2, ch = r2 & 3;
    a_goff[j] = tap * COUT * CIN + row * CIN + ch * 8;
    a_lds[j]  = (tap * 128 + row) * APAD + ch * 8;
  }
  // Y chunks: 528 total; j=0,1 all threads, j=2 only tid<16
  int y_row[3], y_gw[3], y_lds[3], y_coff[3];
  #pragma unroll
  for (int j = 0; j < 3; ++j){
    int idx = tid + j * 256;
    int site = idx >> 2, ch = idx & 3;
    int row = site / 66, col = site - row * 66;
    y_row[j] = row; y_gw[j] = col - 1;
    y_lds[j] = (row * 68 + col) * BPAD + ch * 8;
    y_coff[j] = ch * 8;
  }
  const bool has3 = (tid < 16);

  uint4 pa[6], py[3];

  // ---- fragment read addresses ----
  const int a_base = (wr * 64 + (lane & 15)) * APAD + (lane >> 4) * 8;
  int b_base_ni[4];
  #pragma unroll
  for (int ni = 0; ni < 4; ++ni){
    int n_local = wc * 64 + ni * 16 + (lane & 15);
    b_base_ni[ni] = ((n_local >> 6) * 68 + (n_local & 63)) * BPAD + (lane >> 4) * 8;
  }

  // iteration it: dh = it/8 - 1, ic0 = (it%8)*32
  #define LOAD_IT(IT)                                                              \
    {                                                                              \
      const int tg  = ((IT) >> 3) * 3;                                             \
      const int ic0 = ((IT) & 7) * 32;                                             \
      const unsigned short* ag = nwb + (size_t)tg * COUT * CIN + ic0;              \
      _Pragma("unroll")                                                            \
      for (int j = 0; j < 6; ++j) pa[j] = *(const uint4*)(ag + a_goff[j]);         \
      const int dh = ((IT) >> 3) - 1;                                              \
      _Pragma("unroll")                                                            \
      for (int j = 0; j < 3; ++j){                                                 \
        int gh = h0 + y_row[j] + dh;                                               \
        uint4 v = (uint4){0, 0, 0, 0};                                             \
        bool ok = ((unsigned)gh < 64u) && ((unsigned)y_gw[j] < 64u) &&             \
                  (j < 2 || has3);                                                 \
        if (ok)                                                                    \
          v = *(const uint4*)(ytb + ((size_t)(gh * 64 + y_gw[j])) * CIN + ic0 + y_coff[j]); \
        py[j] = v;                                                                 \
      }                                                                            \
    }

  #define STORE_LDS()                                                              \
    {                                                                              \
      _Pragma("unroll")                                                            \
      for (int j = 0; j < 6; ++j) *(uint4*)(&Wa[a_lds[j]]) = pa[j];                \
      _Pragma("unroll")                                                            \
      for (int j = 0; j < 2; ++j) *(uint4*)(&Yt[y_lds[j]]) = py[j];                \
      if (has3) *(uint4*)(&Yt[y_lds[2]]) = py[2];                                  \
    }

  LOAD_IT(0);
  STORE_LDS();
  __syncthreads();

  for (int it = 0; it < 24; ++it){
    const bool more = (it + 1) < 24;
    if (more){ LOAD_IT(it + 1); }
    #pragma unroll
    for (int tap = 0; tap < 3; ++tap){
      short8 af[4];
      #pragma unroll
      for (int mi = 0; mi < 4; ++mi)
        af[mi] = *(const short8*)&Wa[a_base + (tap * 128 + mi * 16) * APAD];
      #pragma unroll
      for (int ni = 0; ni < 4; ++ni){
        const short8 bf = *(const short8*)&Yt[b_base_ni[ni] + tap * BPAD];
        #pragma unroll
        for (int mi = 0; mi < 4; ++mi)
          acc[mi][ni] = __builtin_amdgcn_mfma_f32_16x16x32_bf16(af[mi], bf, acc[mi][ni], 0, 0, 0);
      }
    }
    __syncthreads();
    if (more){
      STORE_LDS();
    }
    __syncthreads();
  }

  // epilogue: D layout col=lane&15 (hw), row=(lane>>4)*4+reg (oc)
  const int col_l = lane & 15, row_l = (lane >> 4) * 4;
  #pragma unroll
  for (int mi = 0; mi < 4; ++mi){
    #pragma unroll
    for (int r = 0; r < 4; ++r){
      const int ocl = wr * 64 + mi * 16 + row_l + r;
      const float bb = bsh[ocl];
      float* op = out + ((size_t)(b * COUT + oc0 + ocl)) * (HH * WW) + hw0 + wc * 64;
      #pragma unroll
      for (int ni = 0; ni < 4; ++ni)
        op[ni * 16 + col_l] = acc[mi][ni][r] + bb;
    }
  }
  #undef LOAD_IT
  #undef STORE_LDS
}

extern "C" void kernel_launch(void* const* d_in, const int* in_sizes, int n_in,
                              void* d_out, int out_size, void* d_ws, size_t ws_size,
                              hipStream_t stream){
  const float* y      = (const float*)d_in[0];
  const float* finger = (const float*)d_in[1];
  const float* ow     = (const float*)d_in[2];
  const float* wmask  = (const float*)d_in[3];
  const float* fwgt   = (const float*)d_in[4];
  const float* sw1    = (const float*)d_in[5];
  const float* sw2    = (const float*)d_in[6];
  const float* obias  = (const float*)d_in[7];
  const float* bmask  = (const float*)d_in[8];
  const float* fbias  = (const float*)d_in[9];
  const float* bw1    = (const float*)d_in[10];
  const float* bw2    = (const float*)d_in[11];
  float* out = (float*)d_out;
  float* ws  = (float*)d_ws;

  float* stat  = ws + OFF_STAT;
  float* bmean = ws + OFF_BMEAN;
  float* bstd  = ws + OFF_BSTD;
  float* ops   = ws + OFF_OPS;
  float* opq   = ws + OFF_OPQ;
  float* ps    = ws + OFF_PS;
  float* pq    = ws + OFF_PQ;
  float* h     = ws + OFF_H;
  float* style = ws + OFF_STYLE;
  float* nbias = ws + OFF_NBIAS;
  unsigned short* nw  = (unsigned short*)(ws + OFF_NW);
  unsigned short* ytr = (unsigned short*)(ws + OFF_YTR);

  k_ori_part<<<NPART, 256, 0, stream>>>(ow, ops, opq);
  k_ori_final<<<1, 64, 0, stream>>>(ops, opq, stat);
  k_style_h<<<(B * LAT + 255) / 256, 256, 0, stream>>>(finger, sw1, h);
  k_style<<<(B * 2 * WPS + 255) / 256, 256, 0, stream>>>(h, sw2, style);
  k_bias<<<B, COUT, 0, stream>>>(finger, bw1, bw2, fbias, bmask, obias, nbias);
  k_w1_part<<<dim3(NPART, B), 256, 0, stream>>>(ow, fwgt, wmask, style, ps, pq);
  k_w1_final<<<B, 64, 0, stream>>>(ps, pq, bmean, bstd);
  k_new_weight2<<<dim3(COUT, B), 256, 0, stream>>>(ow, fwgt, wmask, style, stat, bmean, bstd, nw);
  k_ytr<<<dim3(HH, B), 256, 0, stream>>>(y, ytr);
  k_conv_mfma5<<<dim3(32, 2, 16), 256, 0, stream>>>(ytr, nw, nbias, out);
}

// Round 7
// 174.668 us; speedup vs baseline: 1.5949x; 1.5949x over previous
//
#include <hip/hip_runtime.h>
#include <math.h>

#define LSLOPE 0.01f

__device__ __forceinline__ float lrelu(float x){ return x >= 0.f ? x : LSLOPE * x; }

typedef __attribute__((ext_vector_type(8))) short short8;
typedef __attribute__((ext_vector_type(4))) float f32x4;

__device__ __forceinline__ unsigned short f2bf(float f){
  union { float f; unsigned u; } v; v.f = f;
  unsigned r = v.u + 0x7FFFu + ((v.u >> 16) & 1u);
  return (unsigned short)(r >> 16);
}

__device__ __forceinline__ void gload_lds16(const unsigned short* g, unsigned short* l){
  __builtin_amdgcn_global_load_lds((const __attribute__((address_space(1))) unsigned int*)(g),
                                   (__attribute__((address_space(3))) unsigned int*)(l), 16, 0, 0);
}

constexpr int B    = 16;
constexpr int CIN  = 256;
constexpr int COUT = 256;
constexpr int HH   = 64;
constexpr int WW   = 64;
constexpr int FD   = 128;
constexpr int LAT  = 128;
constexpr int WPS  = CIN * 9;           // 2304
constexpr int WTOT = COUT * WPS;        // 589824
constexpr int NPART = 64;
constexpr int HP   = 66;                // padded spatial dim

// ---- workspace layout (in floats) ----
constexpr int OFF_STAT  = 0;
constexpr int OFF_BMEAN = 16;
constexpr int OFF_BSTD  = 32;
constexpr int OFF_OPS   = 64;
constexpr int OFF_OPQ   = 128;
constexpr int OFF_PS    = 192;
constexpr int OFF_PQ    = 1216;
constexpr int OFF_H     = 2240;
constexpr int OFF_STYLE = 4288;
constexpr int OFF_NBIAS = 78016;
constexpr int OFF_NW    = 82176;                               // bf16 [16][9][256][256]
constexpr int OFF_YTR   = OFF_NW + (B * 9 * COUT * CIN) / 2;   // bf16 [16][66][66][256] padded

// ---------- global weight stats ----------
__global__ void k_ori_part(const float* __restrict__ ow, float* psum, float* psq){
  const int p = blockIdx.x;
  const int chunk = WTOT / NPART;
  const int base = p * chunk;
  float s = 0.f, q = 0.f;
  for (int i = threadIdx.x; i < chunk; i += 256){
    float v = ow[base + i];
    s += v; q += v * v;
  }
  __shared__ float ss[256], sq[256];
  ss[threadIdx.x] = s; sq[threadIdx.x] = q; __syncthreads();
  for (int st = 128; st > 0; st >>= 1){
    if (threadIdx.x < st){ ss[threadIdx.x] += ss[threadIdx.x + st]; sq[threadIdx.x] += sq[threadIdx.x + st]; }
    __syncthreads();
  }
  if (threadIdx.x == 0){ psum[p] = ss[0]; psq[p] = sq[0]; }
}

__global__ void k_ori_final(const float* __restrict__ psum, const float* __restrict__ psq, float* stat){
  int t = threadIdx.x;
  float s = psum[t], q = psq[t];
  for (int o = 32; o > 0; o >>= 1){ s += __shfl_down(s, o); q += __shfl_down(q, o); }
  if (t == 0){
    const float N = (float)WTOT;
    stat[0] = s / N;
    stat[1] = sqrtf((q - s * s / N) / (N - 1.f));
  }
}

// ---------- style MLP ----------
__global__ void k_style_h(const float* __restrict__ finger, const float* __restrict__ sw1, float* __restrict__ h){
  int idx = blockIdx.x * blockDim.x + threadIdx.x;
  if (idx >= B * LAT) return;
  int b = idx / LAT, l = idx - b * LAT;
  float acc = 0.f;
  for (int f = 0; f < FD; ++f) acc += finger[b * FD + f] * sw1[l * FD + f];
  h[idx] = lrelu(acc);
}

__global__ void k_style(const float* __restrict__ h, const float* __restrict__ sw2, float* __restrict__ style){
  int idx = blockIdx.x * blockDim.x + threadIdx.x;
  if (idx >= B * 2 * WPS) return;
  int b = idx / (2 * WPS), j = idx - b * 2 * WPS;
  float acc = 0.f;
  for (int l = 0; l < LAT; ++l) acc += h[b * LAT + l] * sw2[j * LAT + l];
  style[idx] = acc;
}

// ---------- per-sample bias ----------
__global__ void k_bias(const float* __restrict__ finger, const float* __restrict__ bw1,
                       const float* __restrict__ bw2, const float* __restrict__ fbias,
                       const float* __restrict__ bmask, const float* __restrict__ obias,
                       float* __restrict__ nbias){
  __shared__ float hb[COUT];
  const int b = blockIdx.x, o = threadIdx.x;
  float acc = 0.f;
  for (int f = 0; f < FD; ++f) acc += finger[b * FD + f] * bw1[o * FD + f];
  hb[o] = lrelu(acc);
  __syncthreads();
  float t = 0.f;
  for (int c = 0; c < COUT; ++c) t += hb[c] * bw2[o * COUT + c];
  t = lrelu(t);
  float sb = fbias[o] * t;
  float fwb = (6.f - fminf(fmaxf(bmask[o], 0.f), 6.f)) * (1.f / 6.f);
  nbias[b * COUT + o] = (1.f - fwb) * obias[o] + fwb * sb;
}

// ---------- per-sample w1 stats ----------
__global__ void k_w1_part(const float* __restrict__ ow, const float* __restrict__ fwgt,
                          const float* __restrict__ wmask, const float* __restrict__ style,
                          float* psum, float* psq){
  const int p = blockIdx.x, b = blockIdx.y;
  const float* st = style + b * 2 * WPS;
  const int chunk = WTOT / NPART;
  const int base = p * chunk;
  float s = 0.f, q = 0.f;
  for (int ii = threadIdx.x; ii < chunk; ii += 256){
    int idx = base + ii;
    int o = idx / WPS; int rem = idx - o * WPS; int ci = rem / 9;
    float fw = (6.f - fminf(fmaxf(wmask[o * CIN + ci], 0.f), 6.f)) * (1.f / 6.f);
    float owv = ow[idx];
    float sw = fwgt[idx] * (st[rem] + 1.f) + st[WPS + rem];
    float w1 = owv + fw * (sw - owv);
    s += w1; q += w1 * w1;
  }
  __shared__ float ss[256], sq[256];
  ss[threadIdx.x] = s; sq[threadIdx.x] = q; __syncthreads();
  for (int st2 = 128; st2 > 0; st2 >>= 1){
    if (threadIdx.x < st2){ ss[threadIdx.x] += ss[threadIdx.x + st2]; sq[threadIdx.x] += sq[threadIdx.x + st2]; }
    __syncthreads();
  }
  if (threadIdx.x == 0){ psum[b * NPART + p] = ss[0]; psq[b * NPART + p] = sq[0]; }
}

__global__ void k_w1_final(const float* __restrict__ psum, const float* __restrict__ psq,
                           float* bmean, float* bstd){
  const int b = blockIdx.x;
  int t = threadIdx.x;
  float s = psum[b * NPART + t], q = psq[b * NPART + t];
  for (int o = 32; o > 0; o >>= 1){ s += __shfl_down(s, o); q += __shfl_down(q, o); }
  if (t == 0){
    const float N = (float)WTOT;
    bmean[b] = s / N;
    bstd[b] = sqrtf((q - s * s / N) / (N - 1.f));
  }
}

// ---------- materialize new_weight bf16, tap-major [b][t][oc][ic], coalesced ----------
__global__ __launch_bounds__(256) void k_new_weight2(const float* __restrict__ ow, const float* __restrict__ fwgt,
                                                     const float* __restrict__ wmask, const float* __restrict__ style,
                                                     const float* __restrict__ stat, const float* __restrict__ bmean,
                                                     const float* __restrict__ bstd, unsigned short* __restrict__ nw){
  __shared__ float ows[WPS];
  __shared__ float fws[WPS];
  const int oc = blockIdx.x, b = blockIdx.y;
  const int tid = threadIdx.x;               // = ic
  const float mean_ori = stat[0], std_ori = stat[1];
  const float bm = bmean[b], bs = bstd[b];
  const float* owr = ow + (size_t)oc * WPS;
  const float* fwr = fwgt + (size_t)oc * WPS;
  for (int i = tid; i < WPS; i += 256){ ows[i] = owr[i]; fws[i] = fwr[i]; }
  const float fw = (6.f - fminf(fmaxf(wmask[oc * CIN + tid], 0.f), 6.f)) * (1.f / 6.f);
  const float* st = style + b * 2 * WPS;
  __syncthreads();
  #pragma unroll
  for (int t = 0; t < 9; ++t){
    int rem = tid * 9 + t;
    float owv = ows[rem];
    float sw = fws[rem] * (st[rem] + 1.f) + st[WPS + rem];
    float w1 = owv + fw * (sw - owv);
    float w2 = (w1 - bm) / bs * std_ori + mean_ori;
    nw[((size_t)(b * 9 + t) * COUT + oc) * CIN + tid] = f2bf(owv + fw * (w2 - owv));
  }
}

// ---------- y -> channel-last bf16 with zero halo: ytrp[b][66][66][256] ----------
constexpr int PADT = 264;
__global__ __launch_bounds__(256) void k_ytrp(const float* __restrict__ y, unsigned short* __restrict__ ytrp){
  __shared__ unsigned short t[64 * PADT];
  const int ghp = blockIdx.x;   // 0..65
  const int b = blockIdx.y;
  const int tid = threadIdx.x;
  unsigned short* dst = ytrp + ((size_t)b * HP + ghp) * HP * CIN;
  if (ghp == 0 || ghp == HP - 1){
    for (int c = tid; c < HP * CIN / 8; c += 256) ((uint4*)dst)[c] = (uint4){0, 0, 0, 0};
    return;
  }
  const int h = ghp - 1;
  const float* src = y + (size_t)b * CIN * HH * WW + h * WW;
  #pragma unroll
  for (int k = 0; k < 16; ++k){
    int idx = tid + k * 256;
    int ic = idx >> 4, w4 = (idx & 15) * 4;
    float4 v = *(const float4*)(src + (size_t)ic * HH * WW + w4);
    t[(w4 + 0) * PADT + ic] = f2bf(v.x);
    t[(w4 + 1) * PADT + ic] = f2bf(v.y);
    t[(w4 + 2) * PADT + ic] = f2bf(v.z);
    t[(w4 + 3) * PADT + ic] = f2bf(v.w);
  }
  __syncthreads();
  // write padded row: 66*256 ushorts = 2112 uint4 chunks
  for (int c = tid; c < HP * CIN / 8; c += 256){
    int gwp = c >> 5, icg = (c & 31) * 8;
    uint4 v = (uint4){0, 0, 0, 0};
    if (gwp >= 1 && gwp <= 64) v = *(const uint4*)(&t[(gwp - 1) * PADT + icg]);
    ((uint4*)dst)[c] = v;
  }
}

// ---------- MFMA implicit-GEMM conv: DMA-staged LDS, XOR chunk swizzle ----------
// grid (32 hw-tiles, 2 oc-tiles, 16 b); 256 thr = 4 waves (2x2).
// Loop dh(3) x icb(8): stage A [3 taps][128 oc][32 ic] + Y [2 rows][72 cols][32 ic]
// via global_load_lds(16B), linear LDS rows of 64B with chunk position p = g ^ ((row>>1)&3).
__global__ __launch_bounds__(256, 4) void k_conv_mfma6(const unsigned short* __restrict__ ytrp,
                                                       const unsigned short* __restrict__ nw,
                                                       const float* __restrict__ nbias,
                                                       float* __restrict__ out){
  __shared__ __align__(16) unsigned short Wa[3 * 128 * 32];   // 24576 B
  __shared__ __align__(16) unsigned short Yt[144 * 32];       //  9216 B
  __shared__ float bsh[128];

  const int hwt = blockIdx.x;
  const int oc0 = blockIdx.y * 128;
  const int b   = blockIdx.z;
  const int tid = threadIdx.x;
  const int lane = tid & 63, wid = tid >> 6;
  const int wr = wid >> 1, wc = wid & 1;
  const int hw0 = hwt * 128;
  const int h0  = hwt * 2;

  if (tid < 128) bsh[tid] = nbias[b * COUT + oc0 + tid];

  f32x4 acc[4][4];
  #pragma unroll
  for (int i = 0; i < 4; ++i)
    #pragma unroll
    for (int j = 0; j < 4; ++j) acc[i][j] = (f32x4){0.f, 0.f, 0.f, 0.f};

  const unsigned short* nwb = nw + ((size_t)(b * 9) * COUT + oc0) * CIN;
  const unsigned short* ytb = ytrp + (size_t)b * HP * HP * CIN;

  // ---- A DMA geometry: 24 issues of 16 rows; wave w takes I = w + 4s, s<6 ----
  int a_tap[6], a_go[6];
  unsigned short* a_ld[6];
  #pragma unroll
  for (int s = 0; s < 6; ++s){
    int I = wid + 4 * s;
    int tap = I >> 3, rowbase = (I & 7) * 16;
    int row = rowbase + (lane >> 2), p = lane & 3;
    int g = p ^ ((row >> 1) & 3);
    a_tap[s] = tap;
    a_go[s]  = row * CIN + g * 8;
    a_ld[s]  = &Wa[(tap * 128 + rowbase) * 32];
  }
  // ---- Y DMA geometry: 9 issues of 16 sites (site = srow*72 + scol) ----
  int y_go[3]; unsigned short* y_ld[3]; bool y_has[3];
  #pragma unroll
  for (int s = 0; s < 3; ++s){
    int I = wid + 4 * s;
    y_has[s] = (I < 9);
    int Ic = y_has[s] ? I : 0;
    int site = Ic * 16 + (lane >> 2);
    int srow = (site >= 72) ? 1 : 0;
    int scol = site - srow * 72;
    int gwp  = scol > 65 ? 65 : scol;      // pad sites -> valid dummy addr
    int p = lane & 3, g = p ^ ((site >> 1) & 3);
    y_go[s] = ((h0 + srow + 1) * HP + gwp) * CIN + g * 8;   // + dh*HP*CIN + ic0 at use
    y_ld[s] = &Yt[Ic * 16 * 32];
  }

  // ---- fragment read bases ----
  const int gq = lane >> 4;
  int a_rb[4];
  #pragma unroll
  for (int mi = 0; mi < 4; ++mi){
    int r = wr * 64 + mi * 16 + (lane & 15);
    a_rb[mi] = r * 64 + ((gq ^ ((r >> 1) & 3)) << 4);       // byte offset within tap panel
  }
  int b_site[4];
  #pragma unroll
  for (int ni = 0; ni < 4; ++ni)
    b_site[ni] = wc * 72 + ni * 16 + (lane & 15);

  for (int dh = -1; dh <= 1; ++dh){
    const unsigned short* atap = nwb + (size_t)((dh + 1) * 3) * COUT * CIN;
    const unsigned short* ybase = ytb + (ptrdiff_t)dh * HP * CIN;
    for (int icb = 0; icb < 8; ++icb){
      const int ic0 = icb * 32;
      __syncthreads();
      #pragma unroll
      for (int s = 0; s < 6; ++s)
        gload_lds16(atap + (size_t)a_tap[s] * COUT * CIN + ic0 + a_go[s], a_ld[s]);
      #pragma unroll
      for (int s = 0; s < 3; ++s)
        if (y_has[s]) gload_lds16(ybase + ic0 + y_go[s], y_ld[s]);
      __syncthreads();
      #pragma unroll
      for (int tap = 0; tap < 3; ++tap){
        short8 af[4];
        #pragma unroll
        for (int mi = 0; mi < 4; ++mi)
          af[mi] = *(const short8*)((const char*)Wa + tap * 8192 + a_rb[mi]);
        #pragma unroll
        for (int ni = 0; ni < 4; ++ni){
          const int site = b_site[ni] + tap;
          const int boff = (site << 6) + ((gq ^ ((site >> 1) & 3)) << 4);
          const short8 bf = *(const short8*)((const char*)Yt + boff);
          #pragma unroll
          for (int mi = 0; mi < 4; ++mi)
            acc[mi][ni] = __builtin_amdgcn_mfma_f32_16x16x32_bf16(af[mi], bf, acc[mi][ni], 0, 0, 0);
        }
      }
    }
  }

  // epilogue: D layout col=lane&15 (hw), row=(lane>>4)*4+reg (oc)
  const int col_l = lane & 15, row_l = (lane >> 4) * 4;
  #pragma unroll
  for (int mi = 0; mi < 4; ++mi){
    #pragma unroll
    for (int r = 0; r < 4; ++r){
      const int ocl = wr * 64 + mi * 16 + row_l + r;
      const float bb = bsh[ocl];
      float* op = out + ((size_t)(b * COUT + oc0 + ocl)) * (HH * WW) + hw0 + wc * 64;
      #pragma unroll
      for (int ni = 0; ni < 4; ++ni)
        op[ni * 16 + col_l] = acc[mi][ni][r] + bb;
    }
  }
}

extern "C" void kernel_launch(void* const* d_in, const int* in_sizes, int n_in,
                              void* d_out, int out_size, void* d_ws, size_t ws_size,
                              hipStream_t stream){
  const float* y      = (const float*)d_in[0];
  const float* finger = (const float*)d_in[1];
  const float* ow     = (const float*)d_in[2];
  const float* wmask  = (const float*)d_in[3];
  const float* fwgt   = (const float*)d_in[4];
  const float* sw1    = (const float*)d_in[5];
  const float* sw2    = (const float*)d_in[6];
  const float* obias  = (const float*)d_in[7];
  const float* bmask  = (const float*)d_in[8];
  const float* fbias  = (const float*)d_in[9];
  const float* bw1    = (const float*)d_in[10];
  const float* bw2    = (const float*)d_in[11];
  float* out = (float*)d_out;
  float* ws  = (float*)d_ws;

  float* stat  = ws + OFF_STAT;
  float* bmean = ws + OFF_BMEAN;
  float* bstd  = ws + OFF_BSTD;
  float* ops   = ws + OFF_OPS;
  float* opq   = ws + OFF_OPQ;
  float* ps    = ws + OFF_PS;
  float* pq    = ws + OFF_PQ;
  float* h     = ws + OFF_H;
  float* style = ws + OFF_STYLE;
  float* nbias = ws + OFF_NBIAS;
  unsigned short* nw   = (unsigned short*)(ws + OFF_NW);
  unsigned short* ytrp = (unsigned short*)(ws + OFF_YTR);

  k_ori_part<<<NPART, 256, 0, stream>>>(ow, ops, opq);
  k_ori_final<<<1, 64, 0, stream>>>(ops, opq, stat);
  k_style_h<<<(B * LAT + 255) / 256, 256, 0, stream>>>(finger, sw1, h);
  k_style<<<(B * 2 * WPS + 255) / 256, 256, 0, stream>>>(h, sw2, style);
  k_bias<<<B, COUT, 0, stream>>>(finger, bw1, bw2, fbias, bmask, obias, nbias);
  k_w1_part<<<dim3(NPART, B), 256, 0, stream>>>(ow, fwgt, wmask, style, ps, pq);
  k_w1_final<<<B, 64, 0, stream>>>(ps, pq, bmean, bstd);
  k_new_weight2<<<dim3(COUT, B), 256, 0, stream>>>(ow, fwgt, wmask, style, stat, bmean, bstd, nw);
  k_ytrp<<<dim3(HP, B), 256, 0, stream>>>(y, ytrp);
  k_conv_mfma6<<<dim3(32, 2, 16), 256, 0, stream>>>(ytrp, nw, nbias, out);
}